// Round 1
// baseline (116.211 us; speedup 1.0000x reference)
//
#include <hip/hip_runtime.h>

using f32x4  = __attribute__((ext_vector_type(4))) float;
using u16x8  = __attribute__((ext_vector_type(8))) unsigned short;
using u16x4  = __attribute__((ext_vector_type(4))) unsigned short;
using bf16x8 = __attribute__((ext_vector_type(8))) __bf16;

__device__ __forceinline__ unsigned short f2bf(float f){
  unsigned int u = __builtin_bit_cast(unsigned int, f);
  u += 0x7fffu + ((u >> 16) & 1u);          // RNE to bf16
  return (unsigned short)(u >> 16);
}
__device__ __forceinline__ float bf2f(unsigned short h){
  return __builtin_bit_cast(float, ((unsigned int)h) << 16);
}
__device__ __forceinline__ f32x4 mfma_bf16(u16x8 a, u16x8 b, f32x4 c){
  return __builtin_amdgcn_mfma_f32_16x16x32_bf16(
      __builtin_bit_cast(bf16x8, a), __builtin_bit_cast(bf16x8, b), c, 0, 0, 0);
}

// B=64, L=64, C=256, H*W=64. Block = (b, quarter q) -> 16 pixels. 512 thr = 8 waves.
constexpr int C_  = 256;
constexpr int HW_ = 64;
constexpr int L_  = 64;
constexpr int CHW = C_ * HW_;   // 16384

// LDS operand layout (bf16, 256 c x 16 p): el(c,p) = ((c>>3)*16 + p)*8 + (c&7)
// -> B-fragment for K-chunk kc, lane l: one b128 at kc*512 + (l>>4)*128 + (l&15)*8
// -> staging thread (rows s*8..s*8+7, col p): one b128 at (s*16+p)*8
// -> epilogue rows ro..ro+3 (ro = mt*16 + (l>>4)*4), col m: one b64 at
//    ((ro>>3)*16 + m)*8 + (ro&7)

__global__ __launch_bounds__(512, 2)
void kalman_kernel(const float* __restrict__ z,  const float* __restrict__ Wg,
                   const float* __restrict__ bg, const float* __restrict__ Wp,
                   const float* __restrict__ bp, float* __restrict__ out)
{
  __shared__ unsigned short zbuf[2][4096];
  __shared__ unsigned short sbuf[2][4096];

  // XCD swizzle: siblings (same b, q=0..3) land on the same XCD (launch id mod 8)
  const int lx  = (int)blockIdx.x;
  const int xcd = lx & 7;
  const int loc = lx >> 3;            // 0..31
  const int b   = xcd + 8 * (loc >> 2);
  const int q   = loc & 3;            // pixel quarter (16 px)

  const int t    = (int)threadIdx.x;
  const int lane = t & 63;
  const int wv   = t >> 6;            // wave 0..7
  const int m    = lane & 15;         // A-row-in-tile / pixel col
  const int g    = lane >> 4;         // k-group 0..3

  const float* zg = z + (size_t)b * L_ * CHW + q * 16;  // + l*CHW + c*64 + p

  // ---- W fragments into registers (bf16). wave wv owns M-tiles {2wv, 2wv+1} ----
  u16x8 wgf[2][8], wpf[2][8];
  #pragma unroll
  for (int mi = 0; mi < 2; ++mi){
    const int mt = 2 * wv + mi;
    const float* wgsrc = Wg + (size_t)(mt * 16 + m) * 256 + g * 8;
    const float* wpsrc = Wp + (size_t)(mt * 16 + m) * 256 + g * 8;
    #pragma unroll
    for (int kc = 0; kc < 8; ++kc){
      #pragma unroll
      for (int j = 0; j < 8; ++j) wgf[mi][kc][j] = f2bf(wgsrc[kc * 32 + j]);
      #pragma unroll
      for (int j = 0; j < 8; ++j) wpf[mi][kc][j] = f2bf(wpsrc[kc * 32 + j]);
    }
  }

  // biases for this lane's accumulator rows
  f32x4 bgv[2], bpv[2];
  #pragma unroll
  for (int mi = 0; mi < 2; ++mi){
    const int ro = (2 * wv + mi) * 16 + g * 4;
    bgv[mi] = *(const f32x4*)(bg + ro);
    bpv[mi] = *(const f32x4*)(bp + ro);
  }

  // ---- staging ids: thread t handles rows ss*8..ss*8+7 at pixel sp ----
  const int sp = t & 15;
  const int ss = t >> 4;              // 0..31
  const float* st_src = zg + ss * 8 * 64 + sp;     // + l*CHW + j*64
  const int st_dst = (ss * 16 + sp) * 8;

  // prologue: z_0 -> state buf 0 ; z_1 -> z buf 0
  {
    float v0[8], v1[8];
    #pragma unroll
    for (int j = 0; j < 8; ++j) v0[j] = st_src[j * 64];
    #pragma unroll
    for (int j = 0; j < 8; ++j) v1[j] = st_src[CHW + j * 64];
    u16x8 u0, u1;
    #pragma unroll
    for (int j = 0; j < 8; ++j){ u0[j] = f2bf(v0[j]); u1[j] = f2bf(v1[j]); }
    *(u16x8*)(&sbuf[0][st_dst]) = u0;
    *(u16x8*)(&zbuf[0][st_dst]) = u1;
  }
  __syncthreads();

  const int boff = g * 128 + m * 8;   // B-fragment lane offset (+ kc*512)

  for (int l = 1; l < 64; ++l){
    const unsigned short* zb = zbuf[(l - 1) & 1];  // holds z_l
    const unsigned short* sb = sbuf[(l - 1) & 1];  // holds state_{l-1}

    // prefetch z_{l+1} (global -> regs), hidden under the MFMA phase
    float pf[8];
    if (l < 63){
      const float* src = st_src + (size_t)(l + 1) * CHW;
      #pragma unroll
      for (int j = 0; j < 8; ++j) pf[j] = src[j * 64];
    }

    f32x4 gl[2] = {{0,0,0,0},{0,0,0,0}};
    f32x4 zp[2] = {{0,0,0,0},{0,0,0,0}};
    #pragma unroll
    for (int kc = 0; kc < 8; ++kc){
      u16x8 zf = *(const u16x8*)(zb + kc * 512 + boff);
      u16x8 sf = *(const u16x8*)(sb + kc * 512 + boff);
      gl[0] = mfma_bf16(wgf[0][kc], zf, gl[0]);
      gl[1] = mfma_bf16(wgf[1][kc], zf, gl[1]);
      zp[0] = mfma_bf16(wpf[0][kc], sf, zp[0]);
      zp[1] = mfma_bf16(wpf[1][kc], sf, zp[1]);
    }

    // epilogue: k = sigmoid(gl + bg); z_hat = z' + k (z_i - z'); store state bf16
    unsigned short* sbn = sbuf[l & 1];
    #pragma unroll
    for (int mi = 0; mi < 2; ++mi){
      const int ro = (2 * wv + mi) * 16 + g * 4;
      const int el = ((ro >> 3) * 16 + m) * 8 + (ro & 7);
      u16x4 zi4 = *(const u16x4*)(zb + el);
      u16x4 sh;
      #pragma unroll
      for (int r = 0; r < 4; ++r){
        float x   = gl[mi][r] + bgv[mi][r];
        float k   = 1.0f / (1.0f + __expf(-x));
        float zpr = zp[mi][r] + bpv[mi][r];
        float zi  = bf2f(zi4[r]);
        float zh  = zpr + k * (zi - zpr);
        sh[r] = f2bf(zh);
        if (l == 63)
          out[((size_t)b * 256 + ro + r) * 64 + q * 16 + m] = zh;
      }
      *(u16x4*)(sbn + el) = sh;
    }

    // write prefetched z_{l+1} into the other z buffer
    if (l < 63){
      u16x8 u;
      #pragma unroll
      for (int j = 0; j < 8; ++j) u[j] = f2bf(pf[j]);
      *(u16x8*)(&zbuf[l & 1][st_dst]) = u;
    }
    __syncthreads();
  }
}

extern "C" void kernel_launch(void* const* d_in, const int* in_sizes, int n_in,
                              void* d_out, int out_size, void* d_ws, size_t ws_size,
                              hipStream_t stream)
{
  const float* z  = (const float*)d_in[0];
  const float* Wg = (const float*)d_in[1];
  const float* bg = (const float*)d_in[2];
  const float* Wp = (const float*)d_in[3];
  const float* bp = (const float*)d_in[4];
  float* out = (float*)d_out;
  hipLaunchKernelGGL(kalman_kernel, dim3(256), dim3(512), 0, stream,
                     z, Wg, bg, Wp, bp, out);
}

// Round 2
// 108.863 us; speedup vs baseline: 1.0675x; 1.0675x over previous
//
#include <hip/hip_runtime.h>

using f32x4  = __attribute__((ext_vector_type(4))) float;
using u16x8  = __attribute__((ext_vector_type(8))) unsigned short;
using u16x4  = __attribute__((ext_vector_type(4))) unsigned short;
using bf16x8 = __attribute__((ext_vector_type(8))) __bf16;

__device__ __forceinline__ unsigned short f2bf(float f){
  unsigned int u = __builtin_bit_cast(unsigned int, f);
  u += 0x7fffu + ((u >> 16) & 1u);          // RNE to bf16
  return (unsigned short)(u >> 16);
}
__device__ __forceinline__ float bf2f(unsigned short h){
  return __builtin_bit_cast(float, ((unsigned int)h) << 16);
}
__device__ __forceinline__ f32x4 mfma_bf16(u16x8 a, u16x8 b, f32x4 c){
  return __builtin_amdgcn_mfma_f32_16x16x32_bf16(
      __builtin_bit_cast(bf16x8, a), __builtin_bit_cast(bf16x8, b), c, 0, 0, 0);
}
__device__ __forceinline__ float fast_sigmoid(float x){
  // 1/(1+exp(-x)) = 1/(1+exp2(-x*log2e)); HW rcp/exp ~1ulp, fine vs 2% threshold
  return __builtin_amdgcn_rcpf(1.0f + __builtin_amdgcn_exp2f(-1.44269504f * x));
}

// B=64, L=64, C=256, H*W=64. Block = (b, quarter q) -> 16 pixels. 512 thr = 8 waves.
constexpr int C_  = 256;
constexpr int L_  = 64;
constexpr int CHW = C_ * 64;   // 16384

// LDS operand layout (bf16, 256 c x 16 p): el(c,p) = ((c>>3)*16 + p)*8 + (c&7)
// B-fragment (kc, lane l): one b128 at kc*512 + (l>>4)*128 + (l&15)*8
// staging thread (rows ss*8.., col sp): one b128 at (ss*16+sp)*8
// epilogue rows ro..ro+3: one b64 at ((ro>>3)*16 + m)*8 + (ro&7)

__global__ __launch_bounds__(512, 2)
void kalman_kernel(const float* __restrict__ z,  const float* __restrict__ Wg,
                   const float* __restrict__ bg, const float* __restrict__ Wp,
                   const float* __restrict__ bp, float* __restrict__ out)
{
  __shared__ unsigned short zbuf[3][4096];   // z_l triple buffer (2-step prefetch)
  __shared__ unsigned short sbuf[2][4096];   // state ping-pong

  // XCD swizzle: siblings (same b, q=0..3) land on the same XCD
  const int lx  = (int)blockIdx.x;
  const int xcd = lx & 7;
  const int loc = lx >> 3;
  const int b   = xcd + 8 * (loc >> 2);
  const int q   = loc & 3;

  const int t    = (int)threadIdx.x;
  const int lane = t & 63;
  const int wv   = t >> 6;
  const int m    = lane & 15;
  const int g    = lane >> 4;

  const float* zg = z + (size_t)b * L_ * CHW + q * 16;

  // ---- W fragments into registers (bf16); wave wv owns M-tiles {2wv, 2wv+1} ----
  u16x8 wgf[2][8], wpf[2][8];
  #pragma unroll
  for (int mi = 0; mi < 2; ++mi){
    const int mt = 2 * wv + mi;
    const float* wgsrc = Wg + (size_t)(mt * 16 + m) * 256 + g * 8;
    const float* wpsrc = Wp + (size_t)(mt * 16 + m) * 256 + g * 8;
    #pragma unroll
    for (int kc = 0; kc < 8; ++kc){
      f32x4 a0 = *(const f32x4*)(wgsrc + kc * 32);
      f32x4 a1 = *(const f32x4*)(wgsrc + kc * 32 + 4);
      f32x4 p0 = *(const f32x4*)(wpsrc + kc * 32);
      f32x4 p1 = *(const f32x4*)(wpsrc + kc * 32 + 4);
      #pragma unroll
      for (int j = 0; j < 4; ++j){
        wgf[mi][kc][j]     = f2bf(a0[j]);
        wgf[mi][kc][j + 4] = f2bf(a1[j]);
        wpf[mi][kc][j]     = f2bf(p0[j]);
        wpf[mi][kc][j + 4] = f2bf(p1[j]);
      }
    }
  }

  f32x4 bgv[2], bpv[2];
  #pragma unroll
  for (int mi = 0; mi < 2; ++mi){
    const int ro = (2 * wv + mi) * 16 + g * 4;
    bgv[mi] = *(const f32x4*)(bg + ro);
    bpv[mi] = *(const f32x4*)(bp + ro);
  }

  // staging ids: thread t handles rows ss*8..+7 at pixel sp
  const int sp = t & 15;
  const int ss = t >> 4;
  const float* st_src = zg + ss * 8 * 64 + sp;
  const int st_dst = (ss * 16 + sp) * 8;
  const int boff   = g * 128 + m * 8;

  // ---- prologue: z0 -> sbuf[0] (init state), z1 -> zbuf[1], z2 -> zbuf[2] ----
  {
    float v0[8], v1[8], v2[8];
    #pragma unroll
    for (int j = 0; j < 8; ++j) v0[j] = st_src[j * 64];
    #pragma unroll
    for (int j = 0; j < 8; ++j) v1[j] = st_src[CHW + j * 64];
    #pragma unroll
    for (int j = 0; j < 8; ++j) v2[j] = st_src[2 * CHW + j * 64];
    u16x8 u0, u1, u2;
    #pragma unroll
    for (int j = 0; j < 8; ++j){ u0[j] = f2bf(v0[j]); u1[j] = f2bf(v1[j]); u2[j] = f2bf(v2[j]); }
    *(u16x8*)(&sbuf[0][st_dst]) = u0;
    *(u16x8*)(&zbuf[1][st_dst]) = u1;
    *(u16x8*)(&zbuf[2][st_dst]) = u2;
  }
  __syncthreads();

  // k_1 from z_1 (zbuf[1])
  f32x4 kcur[2];
  {
    f32x4 gl[2] = {{0,0,0,0},{0,0,0,0}};
    #pragma unroll
    for (int kc = 0; kc < 8; ++kc){
      u16x8 zf = *(const u16x8*)(&zbuf[1][kc * 512 + boff]);
      gl[0] = mfma_bf16(wgf[0][kc], zf, gl[0]);
      gl[1] = mfma_bf16(wgf[1][kc], zf, gl[1]);
    }
    #pragma unroll
    for (int mi = 0; mi < 2; ++mi)
      #pragma unroll
      for (int r = 0; r < 4; ++r)
        kcur[mi][r] = fast_sigmoid(gl[mi][r] + bgv[mi][r]);
  }

  for (int l = 1; l < 64; ++l){
    const unsigned short* sb  = sbuf[(l - 1) & 1];
    const unsigned short* zbl = zbuf[l % 3];        // z_l   (blend)
    const unsigned short* zbn = zbuf[(l + 1) % 3];  // z_{l+1} (gain for next step)
    unsigned short* sbw = sbuf[l & 1];
    unsigned short* zbw = zbuf[(l + 2) % 3];

    // prefetch z_{l+2}: issued here, consumed at loop bottom (coverage ~ 1 step)
    float pf[8];
    const bool do_pf = (l <= 61);
    if (do_pf){
      const float* src = st_src + (size_t)(l + 2) * CHW;
      #pragma unroll
      for (int j = 0; j < 8; ++j) pf[j] = src[j * 64];
    }

    // state matvec (split accumulators: 4-deep chains) + gain matvec for l+1
    f32x4 zpA[2] = {{0,0,0,0},{0,0,0,0}};
    f32x4 zpB[2] = {{0,0,0,0},{0,0,0,0}};
    f32x4 gl [2] = {{0,0,0,0},{0,0,0,0}};
    #pragma unroll
    for (int kc = 0; kc < 8; ++kc){
      u16x8 sf = *(const u16x8*)(sb  + kc * 512 + boff);
      u16x8 zf = *(const u16x8*)(zbn + kc * 512 + boff);
      if (kc & 4){
        zpB[0] = mfma_bf16(wpf[0][kc], sf, zpB[0]);
        zpB[1] = mfma_bf16(wpf[1][kc], sf, zpB[1]);
      } else {
        zpA[0] = mfma_bf16(wpf[0][kc], sf, zpA[0]);
        zpA[1] = mfma_bf16(wpf[1][kc], sf, zpA[1]);
      }
      gl[0] = mfma_bf16(wgf[0][kc], zf, gl[0]);
      gl[1] = mfma_bf16(wgf[1][kc], zf, gl[1]);
    }

    // epilogue: blend with k from registers (computed last step)
    #pragma unroll
    for (int mi = 0; mi < 2; ++mi){
      const int ro = (2 * wv + mi) * 16 + g * 4;
      const int el = ((ro >> 3) * 16 + m) * 8 + (ro & 7);
      u16x4 zi4 = *(const u16x4*)(zbl + el);
      u16x4 sh;
      #pragma unroll
      for (int r = 0; r < 4; ++r){
        float zpr = zpA[mi][r] + zpB[mi][r] + bpv[mi][r];
        float zi  = bf2f(zi4[r]);
        float zh  = zpr + kcur[mi][r] * (zi - zpr);
        sh[r] = f2bf(zh);
        if (l == 63)
          out[((size_t)b * 256 + ro + r) * 64 + q * 16 + m] = zh;
      }
      *(u16x4*)(sbw + el) = sh;
    }

    // sigmoid for step l+1 (gl is garbage at l=63; unused)
    #pragma unroll
    for (int mi = 0; mi < 2; ++mi)
      #pragma unroll
      for (int r = 0; r < 4; ++r)
        kcur[mi][r] = fast_sigmoid(gl[mi][r] + bgv[mi][r]);

    // commit prefetched z_{l+2}
    if (do_pf){
      u16x8 u;
      #pragma unroll
      for (int j = 0; j < 8; ++j) u[j] = f2bf(pf[j]);
      *(u16x8*)(zbw + st_dst) = u;
    }
    __syncthreads();
  }
}

extern "C" void kernel_launch(void* const* d_in, const int* in_sizes, int n_in,
                              void* d_out, int out_size, void* d_ws, size_t ws_size,
                              hipStream_t stream)
{
  const float* z  = (const float*)d_in[0];
  const float* Wg = (const float*)d_in[1];
  const float* bg = (const float*)d_in[2];
  const float* Wp = (const float*)d_in[3];
  const float* bp = (const float*)d_in[4];
  float* out = (float*)d_out;
  hipLaunchKernelGGL(kalman_kernel, dim3(256), dim3(512), 0, stream,
                     z, Wg, bg, Wp, bp, out);
}

// Round 3
// 97.270 us; speedup vs baseline: 1.1947x; 1.1192x over previous
//
#include <hip/hip_runtime.h>

using f32x4  = __attribute__((ext_vector_type(4))) float;
using u16x8  = __attribute__((ext_vector_type(8))) unsigned short;
using u16x4  = __attribute__((ext_vector_type(4))) unsigned short;
using bf16x8 = __attribute__((ext_vector_type(8))) __bf16;

__device__ __forceinline__ unsigned short f2bf(float f){
  unsigned int u = __builtin_bit_cast(unsigned int, f);
  u += 0x7fffu + ((u >> 16) & 1u);          // RNE to bf16
  return (unsigned short)(u >> 16);
}
__device__ __forceinline__ float bf2f(unsigned short h){
  return __builtin_bit_cast(float, ((unsigned int)h) << 16);
}
__device__ __forceinline__ unsigned short f2h(float f){
  return __builtin_bit_cast(unsigned short, (_Float16)f);
}
__device__ __forceinline__ float h2f(unsigned short h){
  return (float)__builtin_bit_cast(_Float16, h);
}
__device__ __forceinline__ f32x4 mfma_bf16(u16x8 a, u16x8 b, f32x4 c){
  return __builtin_amdgcn_mfma_f32_16x16x32_bf16(
      __builtin_bit_cast(bf16x8, a), __builtin_bit_cast(bf16x8, b), c, 0, 0, 0);
}
__device__ __forceinline__ float fast_sigmoid(float x){
  return __builtin_amdgcn_rcpf(1.0f + __builtin_amdgcn_exp2f(-1.44269504f * x));
}

constexpr int C_  = 256;
constexpr int L_  = 64;
constexpr int CHW = C_ * 64;   // 16384

// LDS operand layout (bf16/fp16, 256 c x 16 p): el(c,p) = ((c>>3)*16 + p)*8 + (c&7)
// B-fragment (kc, lane): b128 at kc*512 + (lane>>4)*128 + (lane&15)*8
// staging thread: b128 at (ss*16+sp)*8 ; epilogue rows ro..ro+3: b64 at
// ((ro>>3)*16 + m)*8 + (ro&7)

// Raw barrier: LDS ops drained, global prefetch loads stay in flight (no vmcnt drain)
#define BAR_LDS() do {                                        \
    asm volatile("s_waitcnt lgkmcnt(0)" ::: "memory");        \
    __builtin_amdgcn_s_barrier();                             \
    asm volatile("" ::: "memory");                            \
  } while (0)

__global__ __launch_bounds__(512, 2)
void kalman_kernel(const float* __restrict__ z,  const float* __restrict__ Wg,
                   const float* __restrict__ bg, const float* __restrict__ Wp,
                   const float* __restrict__ bp, float* __restrict__ out)
{
  __shared__ unsigned short zbuf[4][4096];   // z ring (3-step prefetch depth)
  __shared__ unsigned short sbuf[2][4096];   // state ping-pong (bf16)
  __shared__ unsigned short kbuf[2][4096];   // gain k ping-pong (fp16)

  // XCD swizzle: siblings (same b, q=0..3) share an XCD's L2 (z lines span q0/q1, q2/q3)
  const int lx  = (int)blockIdx.x;
  const int xcd = lx & 7;
  const int loc = lx >> 3;
  const int b   = xcd + 8 * (loc >> 2);
  const int q   = loc & 3;

  const int t    = (int)threadIdx.x;
  const int lane = t & 63;
  const int wv   = t >> 6;
  const int role = wv >> 2;           // 0 = P (predict+blend), 1 = G (gain, 1 step ahead)
  const int rw   = wv & 3;            // role-local wave id; owns M-tiles rw*4 .. rw*4+3
  const int m    = lane & 15;
  const int g    = lane >> 4;

  const float* zg = z + (size_t)b * L_ * CHW + q * 16;

  // ---- weights for THIS role only: 4 M-tiles x 8 K-chunks (128 VGPRs) ----
  const float* Wsel = (role == 0) ? Wp : Wg;
  const float* bsrc = (role == 0) ? bp : bg;
  u16x8 wf[4][8];
  f32x4 bsel[4];
  #pragma unroll
  for (int mi = 0; mi < 4; ++mi){
    const int mt = rw * 4 + mi;
    const float* src = Wsel + (size_t)(mt * 16 + m) * 256 + g * 8;
    #pragma unroll
    for (int kc = 0; kc < 8; ++kc){
      f32x4 a0 = *(const f32x4*)(src + kc * 32);
      f32x4 a1 = *(const f32x4*)(src + kc * 32 + 4);
      #pragma unroll
      for (int j = 0; j < 4; ++j){
        wf[mi][kc][j]     = f2bf(a0[j]);
        wf[mi][kc][j + 4] = f2bf(a1[j]);
      }
    }
    bsel[mi] = *(const f32x4*)(bsrc + (rw * 4 + mi) * 16 + g * 4);
  }

  // staging ids: thread t stages rows ss*8..+7 at pixel sp
  const int sp = t & 15;
  const int ss = t >> 4;
  const float* st_src = zg + ss * 8 * 64 + sp;
  const int st_dst = (ss * 16 + sp) * 8;
  const int boff   = g * 128 + m * 8;

  // ---- prologue: z0 -> sbuf[0], z1 -> zbuf[1], z2 -> zbuf[2]; issue z3 ----
  {
    float v0[8], v1[8], v2[8];
    #pragma unroll
    for (int j = 0; j < 8; ++j) v0[j] = st_src[j * 64];
    #pragma unroll
    for (int j = 0; j < 8; ++j) v1[j] = st_src[CHW + j * 64];
    #pragma unroll
    for (int j = 0; j < 8; ++j) v2[j] = st_src[2 * CHW + j * 64];
    u16x8 u0, u1, u2;
    #pragma unroll
    for (int j = 0; j < 8; ++j){ u0[j] = f2bf(v0[j]); u1[j] = f2bf(v1[j]); u2[j] = f2bf(v2[j]); }
    *(u16x8*)(&sbuf[0][st_dst]) = u0;
    *(u16x8*)(&zbuf[1][st_dst]) = u1;
    *(u16x8*)(&zbuf[2][st_dst]) = u2;
  }
  float pf[8];
  #pragma unroll
  for (int j = 0; j < 8; ++j) pf[j] = st_src[3 * CHW + j * 64];   // z3 in flight
  __syncthreads();

  // k_1 from z_1 (G-waves only)
  if (role == 1){
    u16x8 zf[8];
    #pragma unroll
    for (int kc = 0; kc < 8; ++kc) zf[kc] = *(const u16x8*)(&zbuf[1][kc * 512 + boff]);
    f32x4 gl[4] = {{0,0,0,0},{0,0,0,0},{0,0,0,0},{0,0,0,0}};
    #pragma unroll
    for (int kc = 0; kc < 8; ++kc)
      #pragma unroll
      for (int mi = 0; mi < 4; ++mi)
        gl[mi] = mfma_bf16(wf[mi][kc], zf[kc], gl[mi]);
    #pragma unroll
    for (int mi = 0; mi < 4; ++mi){
      const int ro = (rw * 4 + mi) * 16 + g * 4;
      const int el = ((ro >> 3) * 16 + m) * 8 + (ro & 7);
      u16x4 kk;
      #pragma unroll
      for (int r = 0; r < 4; ++r) kk[r] = f2h(fast_sigmoid(gl[mi][r] + bsel[mi][r]));
      *(u16x4*)(&kbuf[1][el]) = kk;
    }
  }
  __syncthreads();

  for (int l = 1; l < 64; ++l){
    // commit z_{l+2} (loaded last step -> ~1.5 steps of latency coverage)
    if (l <= 61){
      u16x8 u;
      #pragma unroll
      for (int j = 0; j < 8; ++j) u[j] = f2bf(pf[j]);
      *(u16x8*)(&zbuf[(l + 2) & 3][st_dst]) = u;
    }
    // issue z_{l+3}; stays in flight across the raw barrier
    if (l <= 60){
      const float* src = st_src + (size_t)(l + 3) * CHW;
      #pragma unroll
      for (int j = 0; j < 8; ++j) pf[j] = src[j * 64];
    }

    if (role == 0){
      // ---- P-wave: z' = Wp @ state ; blend with k_l from kbuf ----
      const unsigned short* sb  = sbuf[(l - 1) & 1];
      const unsigned short* zbl = zbuf[l & 3];
      const unsigned short* kb  = kbuf[l & 1];
      unsigned short* sbw = sbuf[l & 1];

      u16x4 zi4[4], k4[4];
      #pragma unroll
      for (int mi = 0; mi < 4; ++mi){
        const int ro = (rw * 4 + mi) * 16 + g * 4;
        const int el = ((ro >> 3) * 16 + m) * 8 + (ro & 7);
        zi4[mi] = *(const u16x4*)(zbl + el);
        k4[mi]  = *(const u16x4*)(kb + el);
      }
      u16x8 sf[8];
      #pragma unroll
      for (int kc = 0; kc < 8; ++kc) sf[kc] = *(const u16x8*)(sb + kc * 512 + boff);

      f32x4 zp[4] = {{0,0,0,0},{0,0,0,0},{0,0,0,0},{0,0,0,0}};
      __builtin_amdgcn_s_setprio(1);
      #pragma unroll
      for (int kc = 0; kc < 8; ++kc)
        #pragma unroll
        for (int mi = 0; mi < 4; ++mi)
          zp[mi] = mfma_bf16(wf[mi][kc], sf[kc], zp[mi]);
      __builtin_amdgcn_s_setprio(0);

      #pragma unroll
      for (int mi = 0; mi < 4; ++mi){
        const int ro = (rw * 4 + mi) * 16 + g * 4;
        const int el = ((ro >> 3) * 16 + m) * 8 + (ro & 7);
        u16x4 sh;
        #pragma unroll
        for (int r = 0; r < 4; ++r){
          float zpr = zp[mi][r] + bsel[mi][r];
          float zi  = bf2f(zi4[mi][r]);
          float zh  = zpr + h2f(k4[mi][r]) * (zi - zpr);
          sh[r] = f2bf(zh);
          if (l == 63)
            out[((size_t)b * 256 + ro + r) * 64 + q * 16 + m] = zh;
        }
        *(u16x4*)(sbw + el) = sh;
      }
    } else {
      // ---- G-wave: k_{l+1} = sigmoid(Wg @ z_{l+1} + bg) ----
      const unsigned short* zb = zbuf[(l + 1) & 3];  // stale at l=63 (k64 unused)
      unsigned short* kw = kbuf[(l + 1) & 1];

      u16x8 zf[8];
      #pragma unroll
      for (int kc = 0; kc < 8; ++kc) zf[kc] = *(const u16x8*)(zb + kc * 512 + boff);

      f32x4 gl[4] = {{0,0,0,0},{0,0,0,0},{0,0,0,0},{0,0,0,0}};
      #pragma unroll
      for (int kc = 0; kc < 8; ++kc)
        #pragma unroll
        for (int mi = 0; mi < 4; ++mi)
          gl[mi] = mfma_bf16(wf[mi][kc], zf[kc], gl[mi]);

      #pragma unroll
      for (int mi = 0; mi < 4; ++mi){
        const int ro = (rw * 4 + mi) * 16 + g * 4;
        const int el = ((ro >> 3) * 16 + m) * 8 + (ro & 7);
        u16x4 kk;
        #pragma unroll
        for (int r = 0; r < 4; ++r) kk[r] = f2h(fast_sigmoid(gl[mi][r] + bsel[mi][r]));
        *(u16x4*)(kw + el) = kk;
      }
    }

    BAR_LDS();
  }
}

extern "C" void kernel_launch(void* const* d_in, const int* in_sizes, int n_in,
                              void* d_out, int out_size, void* d_ws, size_t ws_size,
                              hipStream_t stream)
{
  const float* z  = (const float*)d_in[0];
  const float* Wg = (const float*)d_in[1];
  const float* bg = (const float*)d_in[2];
  const float* Wp = (const float*)d_in[3];
  const float* bp = (const float*)d_in[4];
  float* out = (float*)d_out;
  hipLaunchKernelGGL(kalman_kernel, dim3(256), dim3(512), 0, stream,
                     z, Wg, bg, Wp, bp, out);
}